// Round 24
// baseline (127.169 us; speedup 1.0000x reference)
//
#include <hip/hip_runtime.h>
#include <hip/hip_bf16.h>

typedef __attribute__((ext_vector_type(4))) float f32x4;
typedef __attribute__((ext_vector_type(8))) short bf16x8;
typedef unsigned short u16;
typedef unsigned int u32;

#define QSCALE 0.18033688011112042f  // (1/sqrt(64)) * log2(e), folded into Q proj
#define MASKVAL (-60.0f)             // finite mask: exp2(-60)=8.7e-19, negligible

__device__ __forceinline__ u16 f2bf(float f) {
  union { float f; u32 u; } v; v.f = f;
  u32 r = v.u + 0x7fffu + ((v.u >> 16) & 1u);
  return (u16)(r >> 16);
}

__device__ __forceinline__ u32 cvtpk(float a, float b) {
  u32 r;
  asm("v_cvt_pk_bf16_f32 %0, %1, %2" : "=v"(r) : "v"(a), "v"(b));
  return r;
}

// compiler-visible pack: v_exp_f32 (TRANS) feeding inline-asm gets no
// compiler wait-states (r17-r19); keep all exp consumers intrinsic-visible.
__device__ __forceinline__ u32 cvtpk_safe(float a, float b) {
  __hip_bfloat162 h = __float22bfloat162_rn(float2{a, b});
  union { __hip_bfloat162 h; u32 u; } v; v.h = h;
  return v.u;
}

// native 2^x: single v_exp_f32
__device__ __forceinline__ float nexp2(float x) {
  return __builtin_amdgcn_exp2f(x);
}

// async global->LDS, 16B per lane; LDS dest = base + lane*16 (wave-uniform base)
__device__ __forceinline__ void gl_lds16(const u16* g, u16* l) {
  __builtin_amdgcn_global_load_lds((const __attribute__((address_space(1))) u32*)g,
                                   (__attribute__((address_space(3))) u32*)l, 16, 0, 0);
}

// ---------------- fp32 -> bf16 bulk convert (q,k,v,Wq,Wk,Wv,Wf) ----------------
__global__ __launch_bounds__(256) void conv_kernel(
    const float* __restrict__ q, const float* __restrict__ k, const float* __restrict__ v,
    const float* __restrict__ wq, const float* __restrict__ wk, const float* __restrict__ wv,
    const float* __restrict__ wf, u16* __restrict__ dst)
{
  size_t i = ((size_t)blockIdx.x * 256 + threadIdx.x) * 8;  // 16M elems total
  const float* src; size_t off;
  if (i < ((size_t)3 << 22)) {
    int a = (int)(i >> 22);
    src = (a == 0) ? q : ((a == 1) ? k : v);
    off = i & ((1u << 22) - 1);
  } else {
    size_t j = i - ((size_t)3 << 22);
    int a = (int)(j >> 20);
    src = (a == 0) ? wq : ((a == 1) ? wk : ((a == 2) ? wv : wf));
    off = j & ((1u << 20) - 1);
  }
  float4 x0 = *reinterpret_cast<const float4*>(src + off);
  float4 x1 = *reinterpret_cast<const float4*>(src + off + 4);
  u32 o[4] = {cvtpk(x0.x, x0.y), cvtpk(x0.z, x0.w), cvtpk(x1.x, x1.y), cvtpk(x1.z, x1.w)};
  *reinterpret_cast<uint4*>(dst + i) = *reinterpret_cast<const uint4*>(o);
}

// ---------------- bf16 GEMM: C[M,N]=X[M,K]@W[N,K]^T+b ; BK=64, swizzled LDS ----
struct GArg {
  const u16* X; const u16* W; const float* bias; void* out; int mode; float scale;
};

template<int BM>
__global__ __launch_bounds__(256) void gemm_bf(GArg a0, GArg a1, GArg a2) {
  constexpr int K = 1024, N = 1024;
  constexpr int WNw = (BM == 128) ? 2 : 4;
  constexpr int NI  = (128 / WNw) / 16;
  constexpr int CA  = BM / 32;
  __shared__ __align__(16) u16 lA[BM * 64];
  __shared__ __align__(16) u16 lB[128 * 64];
  GArg a = (blockIdx.z == 0) ? a0 : ((blockIdx.z == 1) ? a1 : a2);
  const int m0 = blockIdx.x * BM, n0 = blockIdx.y * 128;
  const int tid = threadIdx.x, w = tid >> 6, lane = tid & 63;
  const int lr = lane & 15, lg = lane >> 4;
  const int wm = (w / WNw) * 64, wn = (w % WNw) * (128 / WNw);
  const int lrow8 = lane >> 3, lc = lane & 7;
  const int schunk = (lc ^ lrow8) * 8;

  f32x4 acc[4][NI] = {};

  for (int kt = 0; kt < K; kt += 64) {
    #pragma unroll
    for (int c = 0; c < CA; ++c) {
      int row = w * (BM / 4) + c * 8 + lrow8;
      gl_lds16(a.X + (size_t)(m0 + row) * K + kt + schunk, &lA[(w * (BM / 4) + c * 8) * 64]);
    }
    #pragma unroll
    for (int c = 0; c < 4; ++c) {
      int row = w * 32 + c * 8 + lrow8;
      gl_lds16(a.W + (size_t)(n0 + row) * K + kt + schunk, &lB[(w * 32 + c * 8) * 64]);
    }
    __syncthreads();
    #pragma unroll
    for (int h = 0; h < 2; ++h) {
      bf16x8 af[4], bfv[NI];
      #pragma unroll
      for (int i = 0; i < 4; ++i) {
        int r = wm + i * 16 + lr;
        af[i] = *reinterpret_cast<const bf16x8*>(&lA[r * 64 + (((h * 4 + lg) ^ (r & 7)) * 8)]);
      }
      #pragma unroll
      for (int i = 0; i < NI; ++i) {
        int r = wn + i * 16 + lr;
        bfv[i] = *reinterpret_cast<const bf16x8*>(&lB[r * 64 + (((h * 4 + lg) ^ (r & 7)) * 8)]);
      }
      __builtin_amdgcn_s_setprio(1);
      #pragma unroll
      for (int mi = 0; mi < 4; ++mi)
        #pragma unroll
        for (int ni = 0; ni < NI; ++ni)
          acc[mi][ni] = __builtin_amdgcn_mfma_f32_16x16x32_bf16(af[mi], bfv[ni], acc[mi][ni], 0, 0, 0);
      __builtin_amdgcn_s_setprio(0);
    }
    __syncthreads();
  }

  #pragma unroll
  for (int mi = 0; mi < 4; ++mi) {
    #pragma unroll
    for (int ni = 0; ni < NI; ++ni) {
      int col = n0 + wn + ni * 16 + lr;
      float bv = a.bias[col];
      #pragma unroll
      for (int r = 0; r < 4; ++r) {
        int row = m0 + wm + mi * 16 + lg * 4 + r;
        float val = (acc[mi][ni][r] + bv) * a.scale;
        if (a.mode == 2) {
          ((float*)a.out)[(size_t)row * N + col] = val;
        } else {
          int b = row >> 11, s = row & 2047, hh = col >> 6, hd = col & 63;
          u16* O = (u16*)a.out;
          if (a.mode == 0) O[((size_t)(b * 16 + hh) * 2048 + s) * 64 + hd] = f2bf(val);
          else             O[((size_t)(b * 16 + hh) * 64 + hd) * 2048 + s] = f2bf(val);
        }
      }
    }
  }
}

// ---------------- legacy fp32-staging GEMM (ws fallback) -----------------------
template<int IN_BF16, int OUT_MODE>
__global__ __launch_bounds__(256) void gemm_legacy(
    const void* __restrict__ Xv, const float* __restrict__ W,
    const float* __restrict__ bias, void* __restrict__ Outv, float scale)
{
  constexpr int N = 1024, K = 1024;
  __shared__ __align__(16) u16 lA[128 * 32];
  __shared__ __align__(16) u16 lB[128 * 32];
  const int n0 = blockIdx.x * 128, m0 = blockIdx.y * 128;
  const int tid = threadIdx.x;
  const int w = tid >> 6, lane = tid & 63, lr = lane & 15, lg = lane >> 4;
  const int wm = (w >> 1) * 64, wn = (w & 1) * 64;
  f32x4 acc[4][4] = {};
  for (int kt = 0; kt < K; kt += 32) {
    #pragma unroll
    for (int it = 0; it < 4; ++it) {
      int idx = it * 256 + tid, row = idx >> 3, c4 = idx & 7;
      float4 xv = *reinterpret_cast<const float4*>(&W[(size_t)(n0 + row) * K + kt + c4 * 4]);
      u16* dst = &lB[row * 32 + c4 * 4];
      dst[0] = f2bf(xv.x); dst[1] = f2bf(xv.y); dst[2] = f2bf(xv.z); dst[3] = f2bf(xv.w);
    }
    if (IN_BF16 == 0) {
      const float* X = (const float*)Xv;
      #pragma unroll
      for (int it = 0; it < 4; ++it) {
        int idx = it * 256 + tid, row = idx >> 3, c4 = idx & 7;
        float4 xv = *reinterpret_cast<const float4*>(&X[(size_t)(m0 + row) * K + kt + c4 * 4]);
        u16* dst = &lA[row * 32 + c4 * 4];
        dst[0] = f2bf(xv.x); dst[1] = f2bf(xv.y); dst[2] = f2bf(xv.z); dst[3] = f2bf(xv.w);
      }
    } else {
      const u16* X = (const u16*)Xv;
      #pragma unroll
      for (int it = 0; it < 2; ++it) {
        int idx = it * 256 + tid, row = idx >> 2, c = idx & 3;
        *reinterpret_cast<uint4*>(&lA[row * 32 + c * 8]) =
            *reinterpret_cast<const uint4*>(&X[(size_t)(m0 + row) * K + kt + c * 8]);
      }
    }
    __syncthreads();
    bf16x8 af[4], bfr[4];
    #pragma unroll
    for (int i = 0; i < 4; ++i) {
      af[i]  = *reinterpret_cast<const bf16x8*>(&lA[(wm + i * 16 + lr) * 32 + lg * 8]);
      bfr[i] = *reinterpret_cast<const bf16x8*>(&lB[(wn + i * 16 + lr) * 32 + lg * 8]);
    }
    #pragma unroll
    for (int mi = 0; mi < 4; ++mi)
      #pragma unroll
      for (int ni = 0; ni < 4; ++ni)
        acc[mi][ni] = __builtin_amdgcn_mfma_f32_16x16x32_bf16(af[mi], bfr[ni], acc[mi][ni], 0, 0, 0);
    __syncthreads();
  }
  #pragma unroll
  for (int mi = 0; mi < 4; ++mi)
    #pragma unroll
    for (int ni = 0; ni < 4; ++ni) {
      int col = n0 + wn + ni * 16 + lr;
      float bv = bias[col];
      #pragma unroll
      for (int r = 0; r < 4; ++r) {
        int row = m0 + wm + mi * 16 + lg * 4 + r;
        float val = (acc[mi][ni][r] + bv) * scale;
        if (OUT_MODE == 2) {
          ((float*)Outv)[(size_t)row * N + col] = val;
        } else {
          int b = row >> 11, s = row & 2047, h = col >> 6, hd = col & 63;
          u16* O = (u16*)Outv;
          if (OUT_MODE == 0) O[((size_t)(b * 16 + h) * 2048 + s) * 64 + hd] = f2bf(val);
          else               O[((size_t)(b * 16 + h) * 64 + hd) * 2048 + s] = f2bf(val);
        }
      }
    }
}

// ---------------- causal flash attention v13: KVBLK=32, 20KB LDS ---------------
// Round-23 datapath (no-softmax, native v_exp, cvtpk_safe, finite mask) with
// 32-wide k-blocks: K/V dbuf 8KB+8KB, P scratch 4KB -> 20KB total (occupancy
// probe: residency was pinned at 2 blocks/CU with 40KB). Per step: 4 QK MFMA,
// 1 ls MFMA, 4 PV MFMA; nkt = 2t+2; mask applies for kt >= 2t.

__device__ __forceinline__ void seg_step5(
    const bf16x8* aq, f32x4* oacc, float& ls,
    const u16* lK, const u16* lV, char* pwb,
    bool diag, int col0, int qv, int lr, int lg, bf16x8 ones)
{
  const int cs = lr & 7;
  // scores: lane holds S[k = nf*16 + lg*4 + r][q = lr], k-block of 32
  f32x4 sc[2];
  #pragma unroll
  for (int nf = 0; nf < 2; ++nf) {
    const u16* kr = &lK[(nf * 16 + lr) * 64];
    bf16x8 k0 = *reinterpret_cast<const bf16x8*>(&kr[(lg ^ cs) * 8]);
    bf16x8 k1 = *reinterpret_cast<const bf16x8*>(&kr[((4 + lg) ^ cs) * 8]);
    f32x4 z = {};
    __builtin_amdgcn_s_setprio(1);
    z = __builtin_amdgcn_mfma_f32_16x16x32_bf16(k0, aq[0], z, 0, 0, 0);
    z = __builtin_amdgcn_mfma_f32_16x16x32_bf16(k1, aq[1], z, 0, 0, 0);
    __builtin_amdgcn_s_setprio(0);
    sc[nf] = z;
  }
  // hoisted V A-fragments (64 d x 32 k tile, linear rows of 64B; 2-way only)
  bf16x8 va[4];
  #pragma unroll
  for (int df = 0; df < 4; ++df)
    va[df] = *reinterpret_cast<const bf16x8*>(&lV[(df * 16 + lr) * 32 + lg * 8]);
  if (diag) {
    #pragma unroll
    for (int nf = 0; nf < 2; ++nf)
      #pragma unroll
      for (int r = 0; r < 4; ++r)
        if ((col0 + nf * 16 + lg * 4 + r) > qv) sc[nf][r] = MASKVAL;
  }
  // P = exp2(s) -> per-wave scratch (rows of 64B)
  #pragma unroll
  for (int nf = 0; nf < 2; ++nf) {
    uint2 pr;
    pr.x = cvtpk_safe(nexp2(sc[nf][0]), nexp2(sc[nf][1]));
    pr.y = cvtpk_safe(nexp2(sc[nf][2]), nexp2(sc[nf][3]));
    *reinterpret_cast<uint2*>(pwb + lr * 64 + nf * 32 + lg * 8) = pr;
  }
  // B-fragment: P[k = 8*lg + j][q = lr], full k=32 in one bf16x8
  bf16x8 pb = *reinterpret_cast<const bf16x8*>(pwb + lr * 64 + lg * 16);
  f32x4 rs = {};
  rs = __builtin_amdgcn_mfma_f32_16x16x32_bf16(ones, pb, rs, 0, 0, 0);
  ls += rs[0];
  #pragma unroll
  for (int df = 0; df < 4; ++df) {
    __builtin_amdgcn_s_setprio(1);
    oacc[df] = __builtin_amdgcn_mfma_f32_16x16x32_bf16(va[df], pb, oacc[df], 0, 0, 0);
    __builtin_amdgcn_s_setprio(0);
  }
}

__global__ __launch_bounds__(256) void attn_kernel13(
    const u16* __restrict__ Qh, const u16* __restrict__ Kh,
    const u16* __restrict__ Vt, u16* __restrict__ Oa)
{
  __shared__ __align__(16) u16 lK[2][32 * 64];
  __shared__ __align__(16) u16 lV[2][64 * 32];
  __shared__ __align__(16) u16 lP[4][16 * 32];
  const int bh = blockIdx.x;            // bh-fast: head -> fixed XCD
  const int y = blockIdx.y;             // balanced-residency t-permutation
  const int t = (y < 8) ? (31 - y) : ((y < 16) ? (y - 8) : ((y < 24) ? (39 - y) : (y - 16)));
  const int b = bh >> 4, h = bh & 15;
  const u16* Qb = Qh + (size_t)bh * 2048 * 64;
  const u16* Kb = Kh + (size_t)bh * 2048 * 64;
  const u16* Vb = Vt + (size_t)bh * 64 * 2048;
  const int tid = threadIdx.x, w = tid >> 6, lane = tid & 63;
  const int lr = lane & 15, lg = lane >> 4;
  const int lrow8 = lane >> 3, lc = lane & 7;
  const int schunk = (lc ^ lrow8) * 8;
  char* pwb = (char*)lP[w];

  bf16x8 ones;
  #pragma unroll
  for (int j = 0; j < 8; ++j) ones[j] = (short)0x3F80;

  bf16x8 aq[2];
  {
    int qrow = t * 64 + w * 16 + lr;
    aq[0] = *reinterpret_cast<const bf16x8*>(&Qb[(size_t)qrow * 64 + lg * 8]);
    aq[1] = *reinterpret_cast<const bf16x8*>(&Qb[(size_t)qrow * 64 + 32 + lg * 8]);
  }
  f32x4 oacc[4] = {};
  float ls = 0.f;
  const int qv = t * 64 + w * 16 + lr;

  const int nkt = 2 * t + 2;
  const int vrow = w * 16 + (lane >> 2);       // V staging row for this lane
  const int vchunk = (lane & 3) * 8;           // 16B chunk within 64B row
  int cur = 0;

  // prologue: stage kt=0
  gl_lds16(Kb + (size_t)(w * 8 + lrow8) * 64 + schunk, &lK[0][(w * 8) * 64]);
  gl_lds16(Vb + (size_t)vrow * 2048 + vchunk, &lV[0][(w * 16) * 32]);
  __syncthreads();

  for (int kt = 0; kt < nkt; ++kt) {
    if (kt + 1 < nkt) {
      gl_lds16(Kb + (size_t)((kt + 1) * 32 + w * 8 + lrow8) * 64 + schunk, &lK[cur ^ 1][(w * 8) * 64]);
      gl_lds16(Vb + (size_t)vrow * 2048 + (kt + 1) * 32 + vchunk, &lV[cur ^ 1][(w * 16) * 32]);
    }
    seg_step5(aq, oacc, ls, lK[cur], lV[cur], pwb, kt >= 2 * t, kt * 32, qv, lr, lg, ones);
    if (kt + 1 < nkt) __syncthreads();
    cur ^= 1;
  }

  float inv = 1.0f / ls;
  #pragma unroll
  for (int df = 0; df < 4; ++df) {
    uint2 pa;
    pa.x = cvtpk(oacc[df][0] * inv, oacc[df][1] * inv);
    pa.y = cvtpk(oacc[df][2] * inv, oacc[df][3] * inv);
    *reinterpret_cast<uint2*>(&Oa[(size_t)(b * 2048 + qv) * 1024 + h * 64 + df * 16 + lg * 4]) = pa;
  }
}

extern "C" void kernel_launch(void* const* d_in, const int* in_sizes, int n_in,
                              void* d_out, int out_size, void* d_ws, size_t ws_size,
                              hipStream_t stream) {
  const float* q  = (const float*)d_in[0];
  const float* k  = (const float*)d_in[1];
  const float* v  = (const float*)d_in[2];
  const float* Wq = (const float*)d_in[4];
  const float* bq = (const float*)d_in[5];
  const float* Wk = (const float*)d_in[6];
  const float* bk = (const float*)d_in[7];
  const float* Wv = (const float*)d_in[8];
  const float* bv = (const float*)d_in[9];
  const float* Wf = (const float*)d_in[10];
  const float* bf = (const float*)d_in[11];

  if (ws_size >= ((size_t)64 << 20)) {
    u16* wsb = (u16*)d_ws;
    u16* qb  = wsb;
    u16* kb  = wsb + (1u << 22);
    u16* vb  = wsb + ((size_t)2 << 22);
    u16* wqb = wsb + ((size_t)3 << 22);
    u16* wkb = wqb + (1u << 20);
    u16* wvb = wkb + (1u << 20);
    u16* wfb = wvb + (1u << 20);
    u16* Qh  = wsb + ((size_t)1 << 24);
    u16* Kh  = Qh + (1u << 22);
    u16* Vt  = Kh + (1u << 22);
    u16* Oa  = Vt + (1u << 22);

    conv_kernel<<<8192, 256, 0, stream>>>(q, k, v, Wq, Wk, Wv, Wf, wsb);

    GArg gq{qb, wqb, bq, Qh, 0, QSCALE};
    GArg gk{kb, wkb, bk, Kh, 0, 1.0f};
    GArg gv{vb, wvb, bv, Vt, 1, 1.0f};
    gemm_bf<128><<<dim3(32, 8, 3), 256, 0, stream>>>(gq, gk, gv);

    attn_kernel13<<<dim3(32, 32), 256, 0, stream>>>(Qh, Kh, Vt, Oa);

    GArg gf{Oa, wfb, bf, d_out, 2, 1.0f};
    gemm_bf<64><<<dim3(64, 8, 1), 256, 0, stream>>>(gf, gf, gf);
  } else {
    // fallback: fp32-staging GEMMs (32 MB ws)
    u16* Qh = (u16*)d_ws;
    u16* Kh = Qh + (size_t)4096 * 1024;
    u16* Vt = Kh + (size_t)4096 * 1024;
    u16* Oa = Vt + (size_t)4096 * 1024;
    dim3 gg(8, 32), gb(256);
    gemm_legacy<0, 0><<<gg, gb, 0, stream>>>(q, Wq, bq, Qh, QSCALE);
    gemm_legacy<0, 0><<<gg, gb, 0, stream>>>(k, Wk, bk, Kh, 1.0f);
    gemm_legacy<0, 1><<<gg, gb, 0, stream>>>(v, Wv, bv, Vt, 1.0f);
    attn_kernel13<<<dim3(32, 32), gb, 0, stream>>>(Qh, Kh, Vt, Oa);
    gemm_legacy<1, 2><<<gg, gb, 0, stream>>>(Oa, Wf, bf, (float*)d_out, 1.0f);
  }
}

// Round 25
// 114.213 us; speedup vs baseline: 1.1134x; 1.1134x over previous
//
#include <hip/hip_runtime.h>
#include <hip/hip_bf16.h>

typedef __attribute__((ext_vector_type(4))) float f32x4;
typedef __attribute__((ext_vector_type(8))) short bf16x8;
typedef unsigned short u16;
typedef unsigned int u32;

#define QSCALE 0.18033688011112042f  // (1/sqrt(64)) * log2(e), folded into Q proj
#define MASKVAL (-60.0f)             // finite mask: exp2(-60)=8.7e-19, negligible

__device__ __forceinline__ u16 f2bf(float f) {
  union { float f; u32 u; } v; v.f = f;
  u32 r = v.u + 0x7fffu + ((v.u >> 16) & 1u);
  return (u16)(r >> 16);
}

__device__ __forceinline__ u32 cvtpk(float a, float b) {
  u32 r;
  asm("v_cvt_pk_bf16_f32 %0, %1, %2" : "=v"(r) : "v"(a), "v"(b));
  return r;
}

// compiler-visible pack: v_exp_f32 (TRANS) feeding inline-asm gets no
// compiler wait-states (r17-r19); keep all exp consumers intrinsic-visible.
__device__ __forceinline__ u32 cvtpk_safe(float a, float b) {
  __hip_bfloat162 h = __float22bfloat162_rn(float2{a, b});
  union { __hip_bfloat162 h; u32 u; } v; v.h = h;
  return v.u;
}

// native 2^x: single v_exp_f32
__device__ __forceinline__ float nexp2(float x) {
  return __builtin_amdgcn_exp2f(x);
}

// async global->LDS, 16B per lane; LDS dest = base + lane*16 (wave-uniform base)
__device__ __forceinline__ void gl_lds16(const u16* g, u16* l) {
  __builtin_amdgcn_global_load_lds((const __attribute__((address_space(1))) u32*)g,
                                   (__attribute__((address_space(3))) u32*)l, 16, 0, 0);
}

// ---------------- fp32 -> bf16 bulk convert (q,k,v,Wq,Wk,Wv,Wf) ----------------
__global__ __launch_bounds__(256) void conv_kernel(
    const float* __restrict__ q, const float* __restrict__ k, const float* __restrict__ v,
    const float* __restrict__ wq, const float* __restrict__ wk, const float* __restrict__ wv,
    const float* __restrict__ wf, u16* __restrict__ dst)
{
  size_t i = ((size_t)blockIdx.x * 256 + threadIdx.x) * 8;  // 16M elems total
  const float* src; size_t off;
  if (i < ((size_t)3 << 22)) {
    int a = (int)(i >> 22);
    src = (a == 0) ? q : ((a == 1) ? k : v);
    off = i & ((1u << 22) - 1);
  } else {
    size_t j = i - ((size_t)3 << 22);
    int a = (int)(j >> 20);
    src = (a == 0) ? wq : ((a == 1) ? wk : ((a == 2) ? wv : wf));
    off = j & ((1u << 20) - 1);
  }
  float4 x0 = *reinterpret_cast<const float4*>(src + off);
  float4 x1 = *reinterpret_cast<const float4*>(src + off + 4);
  u32 o[4] = {cvtpk(x0.x, x0.y), cvtpk(x0.z, x0.w), cvtpk(x1.x, x1.y), cvtpk(x1.z, x1.w)};
  *reinterpret_cast<uint4*>(dst + i) = *reinterpret_cast<const uint4*>(o);
}

// ---------------- bf16 GEMM: C[M,N]=X[M,K]@W[N,K]^T+b ; BK=64, swizzled LDS ----
struct GArg {
  const u16* X; const u16* W; const float* bias; void* out; int mode; float scale;
};

template<int BM>
__global__ __launch_bounds__(256) void gemm_bf(GArg a0, GArg a1, GArg a2) {
  constexpr int K = 1024, N = 1024;
  constexpr int WNw = (BM == 128) ? 2 : 4;
  constexpr int NI  = (128 / WNw) / 16;
  constexpr int CA  = BM / 32;
  __shared__ __align__(16) u16 lA[BM * 64];
  __shared__ __align__(16) u16 lB[128 * 64];
  GArg a = (blockIdx.z == 0) ? a0 : ((blockIdx.z == 1) ? a1 : a2);
  const int m0 = blockIdx.x * BM, n0 = blockIdx.y * 128;
  const int tid = threadIdx.x, w = tid >> 6, lane = tid & 63;
  const int lr = lane & 15, lg = lane >> 4;
  const int wm = (w / WNw) * 64, wn = (w % WNw) * (128 / WNw);
  const int lrow8 = lane >> 3, lc = lane & 7;
  const int schunk = (lc ^ lrow8) * 8;

  f32x4 acc[4][NI] = {};

  for (int kt = 0; kt < K; kt += 64) {
    #pragma unroll
    for (int c = 0; c < CA; ++c) {
      int row = w * (BM / 4) + c * 8 + lrow8;
      gl_lds16(a.X + (size_t)(m0 + row) * K + kt + schunk, &lA[(w * (BM / 4) + c * 8) * 64]);
    }
    #pragma unroll
    for (int c = 0; c < 4; ++c) {
      int row = w * 32 + c * 8 + lrow8;
      gl_lds16(a.W + (size_t)(n0 + row) * K + kt + schunk, &lB[(w * 32 + c * 8) * 64]);
    }
    __syncthreads();
    #pragma unroll
    for (int h = 0; h < 2; ++h) {
      bf16x8 af[4], bfv[NI];
      #pragma unroll
      for (int i = 0; i < 4; ++i) {
        int r = wm + i * 16 + lr;
        af[i] = *reinterpret_cast<const bf16x8*>(&lA[r * 64 + (((h * 4 + lg) ^ (r & 7)) * 8)]);
      }
      #pragma unroll
      for (int i = 0; i < NI; ++i) {
        int r = wn + i * 16 + lr;
        bfv[i] = *reinterpret_cast<const bf16x8*>(&lB[r * 64 + (((h * 4 + lg) ^ (r & 7)) * 8)]);
      }
      __builtin_amdgcn_s_setprio(1);
      #pragma unroll
      for (int mi = 0; mi < 4; ++mi)
        #pragma unroll
        for (int ni = 0; ni < NI; ++ni)
          acc[mi][ni] = __builtin_amdgcn_mfma_f32_16x16x32_bf16(af[mi], bfv[ni], acc[mi][ni], 0, 0, 0);
      __builtin_amdgcn_s_setprio(0);
    }
    __syncthreads();
  }

  #pragma unroll
  for (int mi = 0; mi < 4; ++mi) {
    #pragma unroll
    for (int ni = 0; ni < NI; ++ni) {
      int col = n0 + wn + ni * 16 + lr;
      float bv = a.bias[col];
      #pragma unroll
      for (int r = 0; r < 4; ++r) {
        int row = m0 + wm + mi * 16 + lg * 4 + r;
        float val = (acc[mi][ni][r] + bv) * a.scale;
        if (a.mode == 2) {
          ((float*)a.out)[(size_t)row * N + col] = val;
        } else {
          int b = row >> 11, s = row & 2047, hh = col >> 6, hd = col & 63;
          u16* O = (u16*)a.out;
          if (a.mode == 0) O[((size_t)(b * 16 + hh) * 2048 + s) * 64 + hd] = f2bf(val);
          else             O[((size_t)(b * 16 + hh) * 64 + hd) * 2048 + s] = f2bf(val);
        }
      }
    }
  }
}

// ---------------- legacy fp32-staging GEMM (ws fallback) -----------------------
template<int IN_BF16, int OUT_MODE>
__global__ __launch_bounds__(256) void gemm_legacy(
    const void* __restrict__ Xv, const float* __restrict__ W,
    const float* __restrict__ bias, void* __restrict__ Outv, float scale)
{
  constexpr int N = 1024, K = 1024;
  __shared__ __align__(16) u16 lA[128 * 32];
  __shared__ __align__(16) u16 lB[128 * 32];
  const int n0 = blockIdx.x * 128, m0 = blockIdx.y * 128;
  const int tid = threadIdx.x;
  const int w = tid >> 6, lane = tid & 63, lr = lane & 15, lg = lane >> 4;
  const int wm = (w >> 1) * 64, wn = (w & 1) * 64;
  f32x4 acc[4][4] = {};
  for (int kt = 0; kt < K; kt += 32) {
    #pragma unroll
    for (int it = 0; it < 4; ++it) {
      int idx = it * 256 + tid, row = idx >> 3, c4 = idx & 7;
      float4 xv = *reinterpret_cast<const float4*>(&W[(size_t)(n0 + row) * K + kt + c4 * 4]);
      u16* dst = &lB[row * 32 + c4 * 4];
      dst[0] = f2bf(xv.x); dst[1] = f2bf(xv.y); dst[2] = f2bf(xv.z); dst[3] = f2bf(xv.w);
    }
    if (IN_BF16 == 0) {
      const float* X = (const float*)Xv;
      #pragma unroll
      for (int it = 0; it < 4; ++it) {
        int idx = it * 256 + tid, row = idx >> 3, c4 = idx & 7;
        float4 xv = *reinterpret_cast<const float4*>(&X[(size_t)(m0 + row) * K + kt + c4 * 4]);
        u16* dst = &lA[row * 32 + c4 * 4];
        dst[0] = f2bf(xv.x); dst[1] = f2bf(xv.y); dst[2] = f2bf(xv.z); dst[3] = f2bf(xv.w);
      }
    } else {
      const u16* X = (const u16*)Xv;
      #pragma unroll
      for (int it = 0; it < 2; ++it) {
        int idx = it * 256 + tid, row = idx >> 2, c = idx & 3;
        *reinterpret_cast<uint4*>(&lA[row * 32 + c * 8]) =
            *reinterpret_cast<const uint4*>(&X[(size_t)(m0 + row) * K + kt + c * 8]);
      }
    }
    __syncthreads();
    bf16x8 af[4], bfr[4];
    #pragma unroll
    for (int i = 0; i < 4; ++i) {
      af[i]  = *reinterpret_cast<const bf16x8*>(&lA[(wm + i * 16 + lr) * 32 + lg * 8]);
      bfr[i] = *reinterpret_cast<const bf16x8*>(&lB[(wn + i * 16 + lr) * 32 + lg * 8]);
    }
    #pragma unroll
    for (int mi = 0; mi < 4; ++mi)
      #pragma unroll
      for (int ni = 0; ni < 4; ++ni)
        acc[mi][ni] = __builtin_amdgcn_mfma_f32_16x16x32_bf16(af[mi], bfr[ni], acc[mi][ni], 0, 0, 0);
    __syncthreads();
  }
  #pragma unroll
  for (int mi = 0; mi < 4; ++mi)
    #pragma unroll
    for (int ni = 0; ni < 4; ++ni) {
      int col = n0 + wn + ni * 16 + lr;
      float bv = bias[col];
      #pragma unroll
      for (int r = 0; r < 4; ++r) {
        int row = m0 + wm + mi * 16 + lg * 4 + r;
        float val = (acc[mi][ni][r] + bv) * scale;
        if (OUT_MODE == 2) {
          ((float*)Outv)[(size_t)row * N + col] = val;
        } else {
          int b = row >> 11, s = row & 2047, h = col >> 6, hd = col & 63;
          u16* O = (u16*)Outv;
          if (OUT_MODE == 0) O[((size_t)(b * 16 + h) * 2048 + s) * 64 + hd] = f2bf(val);
          else               O[((size_t)(b * 16 + h) * 64 + hd) * 2048 + s] = f2bf(val);
        }
      }
    }
}

// ---------------- causal flash attention v14: 2 steps per barrier --------------
// Round-23 datapath (seg_step4 unchanged: no-softmax, native v_exp, cvtpk_safe,
// V-read hoist, finite mask). r24 measured ~600cy fixed overhead per barrier
// interval -> process TWO kt per interval with 4-deep K/V buffers; barrier
// count halves. Buffer (kt+2)&3 was last read before the previous barrier ->
// restaging after it is race-free.

__device__ __forceinline__ void seg_step4(
    const bf16x8* aq, f32x4* oacc, float& ls,
    const u16* lK, const u16* lV, char* pwb,
    bool diag, int col0, int qv, int lr, int lg, bf16x8 ones)
{
  const int cs = lr & 7;
  f32x4 sc[4];
  #pragma unroll
  for (int nf = 0; nf < 4; ++nf) {
    const u16* kr = &lK[(nf * 16 + lr) * 64];
    bf16x8 k0 = *reinterpret_cast<const bf16x8*>(&kr[(lg ^ cs) * 8]);
    bf16x8 k1 = *reinterpret_cast<const bf16x8*>(&kr[((4 + lg) ^ cs) * 8]);
    f32x4 z = {};
    __builtin_amdgcn_s_setprio(1);
    z = __builtin_amdgcn_mfma_f32_16x16x32_bf16(k0, aq[0], z, 0, 0, 0);
    z = __builtin_amdgcn_mfma_f32_16x16x32_bf16(k1, aq[1], z, 0, 0, 0);
    __builtin_amdgcn_s_setprio(0);
    sc[nf] = z;
  }
  // hoisted V fragments: overlap their LDS latency with the exp/pack chain
  bf16x8 vv0[4], vv1[4];
  #pragma unroll
  for (int df = 0; df < 4; ++df) {
    const u16* vr = &lV[(df * 16 + lr) * 64];
    vv0[df] = *reinterpret_cast<const bf16x8*>(&vr[(lg ^ cs) * 8]);
    vv1[df] = *reinterpret_cast<const bf16x8*>(&vr[((4 + lg) ^ cs) * 8]);
  }
  if (diag) {
    #pragma unroll
    for (int nf = 0; nf < 4; ++nf)
      #pragma unroll
      for (int r = 0; r < 4; ++r)
        if ((col0 + nf * 16 + lg * 4 + r) > qv) sc[nf][r] = MASKVAL;
  }
  #pragma unroll
  for (int nf = 0; nf < 4; ++nf) {
    float p0 = nexp2(sc[nf][0]), p1 = nexp2(sc[nf][1]);
    float p2 = nexp2(sc[nf][2]), p3 = nexp2(sc[nf][3]);
    uint2 pr;
    pr.x = cvtpk_safe(p0, p1);
    pr.y = cvtpk_safe(p2, p3);
    *reinterpret_cast<uint2*>(pwb + lr * 128 + ((32 * nf + 8 * lg) ^ (cs << 4))) = pr;
  }
  bf16x8 pb0 = *reinterpret_cast<const bf16x8*>(pwb + lr * 128 + 16 * (lg ^ cs));
  bf16x8 pb1 = *reinterpret_cast<const bf16x8*>(pwb + lr * 128 + 16 * ((4 + lg) ^ cs));
  f32x4 rs = {};
  rs = __builtin_amdgcn_mfma_f32_16x16x32_bf16(ones, pb0, rs, 0, 0, 0);
  rs = __builtin_amdgcn_mfma_f32_16x16x32_bf16(ones, pb1, rs, 0, 0, 0);
  ls += rs[0];
  #pragma unroll
  for (int df = 0; df < 4; ++df) {
    __builtin_amdgcn_s_setprio(1);
    oacc[df] = __builtin_amdgcn_mfma_f32_16x16x32_bf16(vv0[df], pb0, oacc[df], 0, 0, 0);
    oacc[df] = __builtin_amdgcn_mfma_f32_16x16x32_bf16(vv1[df], pb1, oacc[df], 0, 0, 0);
    __builtin_amdgcn_s_setprio(0);
  }
}

__global__ __launch_bounds__(256) void attn_kernel14(
    const u16* __restrict__ Qh, const u16* __restrict__ Kh,
    const u16* __restrict__ Vt, u16* __restrict__ Oa)
{
  __shared__ __align__(16) u16 lK[4][64 * 64];
  __shared__ __align__(16) u16 lV[4][64 * 64];
  __shared__ __align__(16) u16 lP[4][16 * 64];
  const int bh = blockIdx.x;            // bh-fast: head -> fixed XCD
  const int y = blockIdx.y;             // balanced-residency t-permutation
  const int t = (y < 8) ? (31 - y) : ((y < 16) ? (y - 8) : ((y < 24) ? (39 - y) : (y - 16)));
  const int b = bh >> 4, h = bh & 15;
  const u16* Qb = Qh + (size_t)bh * 2048 * 64;
  const u16* Kb = Kh + (size_t)bh * 2048 * 64;
  const u16* Vb = Vt + (size_t)bh * 64 * 2048;
  const int tid = threadIdx.x, w = tid >> 6, lane = tid & 63;
  const int lr = lane & 15, lg = lane >> 4;
  const int lrow8 = lane >> 3, lc = lane & 7;
  const int schunk = (lc ^ lrow8) * 8;
  char* pwb = (char*)lP[w];

  bf16x8 ones;
  #pragma unroll
  for (int j = 0; j < 8; ++j) ones[j] = (short)0x3F80;

  bf16x8 aq[2];
  {
    int qrow = t * 64 + w * 16 + lr;
    aq[0] = *reinterpret_cast<const bf16x8*>(&Qb[(size_t)qrow * 64 + lg * 8]);
    aq[1] = *reinterpret_cast<const bf16x8*>(&Qb[(size_t)qrow * 64 + 32 + lg * 8]);
  }
  f32x4 oacc[4] = {};
  float ls = 0.f;
  const int qv = t * 64 + w * 16 + lr;

  const int nkt = t + 1;
  const int srow = w * 16 + lrow8;      // staging rows w*16+{0..7} and +8

  auto stage = [&](int buf, int kt) {
    #pragma unroll
    for (int c = 0; c < 2; ++c) {
      int row = w * 16 + c * 8 + lrow8;
      gl_lds16(Kb + (size_t)(kt * 64 + row) * 64 + schunk, &lK[buf][(w * 16 + c * 8) * 64]);
      gl_lds16(Vb + (size_t)row * 2048 + kt * 64 + schunk, &lV[buf][(w * 16 + c * 8) * 64]);
    }
  };
  (void)srow;

  // prologue: stage kt=0 (and kt=1 if present)
  stage(0, 0);
  if (nkt > 1) stage(1, 1);
  __syncthreads();

  for (int kt = 0; kt < nkt; kt += 2) {
    if (kt + 2 < nkt) stage((kt + 2) & 3, kt + 2);
    if (kt + 3 < nkt) stage((kt + 3) & 3, kt + 3);
    seg_step4(aq, oacc, ls, lK[kt & 3], lV[kt & 3], pwb, kt == t, kt * 64, qv, lr, lg, ones);
    if (kt + 1 < nkt)
      seg_step4(aq, oacc, ls, lK[(kt + 1) & 3], lV[(kt + 1) & 3], pwb, kt + 1 == t, (kt + 1) * 64, qv, lr, lg, ones);
    if (kt + 2 < nkt) __syncthreads();
  }

  float inv = 1.0f / ls;
  #pragma unroll
  for (int df = 0; df < 4; ++df) {
    uint2 pa;
    pa.x = cvtpk(oacc[df][0] * inv, oacc[df][1] * inv);
    pa.y = cvtpk(oacc[df][2] * inv, oacc[df][3] * inv);
    *reinterpret_cast<uint2*>(&Oa[(size_t)(b * 2048 + qv) * 1024 + h * 64 + df * 16 + lg * 4]) = pa;
  }
}

extern "C" void kernel_launch(void* const* d_in, const int* in_sizes, int n_in,
                              void* d_out, int out_size, void* d_ws, size_t ws_size,
                              hipStream_t stream) {
  const float* q  = (const float*)d_in[0];
  const float* k  = (const float*)d_in[1];
  const float* v  = (const float*)d_in[2];
  const float* Wq = (const float*)d_in[4];
  const float* bq = (const float*)d_in[5];
  const float* Wk = (const float*)d_in[6];
  const float* bk = (const float*)d_in[7];
  const float* Wv = (const float*)d_in[8];
  const float* bv = (const float*)d_in[9];
  const float* Wf = (const float*)d_in[10];
  const float* bf = (const float*)d_in[11];

  if (ws_size >= ((size_t)64 << 20)) {
    u16* wsb = (u16*)d_ws;
    u16* qb  = wsb;
    u16* kb  = wsb + (1u << 22);
    u16* vb  = wsb + ((size_t)2 << 22);
    u16* wqb = wsb + ((size_t)3 << 22);
    u16* wkb = wqb + (1u << 20);
    u16* wvb = wkb + (1u << 20);
    u16* wfb = wvb + (1u << 20);
    u16* Qh  = wsb + ((size_t)1 << 24);
    u16* Kh  = Qh + (1u << 22);
    u16* Vt  = Kh + (1u << 22);
    u16* Oa  = Vt + (1u << 22);

    conv_kernel<<<8192, 256, 0, stream>>>(q, k, v, Wq, Wk, Wv, Wf, wsb);

    GArg gq{qb, wqb, bq, Qh, 0, QSCALE};
    GArg gk{kb, wkb, bk, Kh, 0, 1.0f};
    GArg gv{vb, wvb, bv, Vt, 1, 1.0f};
    gemm_bf<128><<<dim3(32, 8, 3), 256, 0, stream>>>(gq, gk, gv);

    attn_kernel14<<<dim3(32, 32), 256, 0, stream>>>(Qh, Kh, Vt, Oa);

    GArg gf{Oa, wfb, bf, d_out, 2, 1.0f};
    gemm_bf<64><<<dim3(64, 8, 1), 256, 0, stream>>>(gf, gf, gf);
  } else {
    // fallback: fp32-staging GEMMs (32 MB ws)
    u16* Qh = (u16*)d_ws;
    u16* Kh = Qh + (size_t)4096 * 1024;
    u16* Vt = Kh + (size_t)4096 * 1024;
    u16* Oa = Vt + (size_t)4096 * 1024;
    dim3 gg(8, 32), gb(256);
    gemm_legacy<0, 0><<<gg, gb, 0, stream>>>(q, Wq, bq, Qh, QSCALE);
    gemm_legacy<0, 0><<<gg, gb, 0, stream>>>(k, Wk, bk, Kh, 1.0f);
    gemm_legacy<0, 1><<<gg, gb, 0, stream>>>(v, Wv, bv, Vt, 1.0f);
    attn_kernel14<<<dim3(32, 32), gb, 0, stream>>>(Qh, Kh, Vt, Oa);
    gemm_legacy<1, 2><<<gg, gb, 0, stream>>>(Oa, Wf, bf, (float*)d_out, 1.0f);
  }
}

// Round 26
// 107.216 us; speedup vs baseline: 1.1861x; 1.0653x over previous
//
#include <hip/hip_runtime.h>
#include <hip/hip_bf16.h>

typedef __attribute__((ext_vector_type(4))) float f32x4;
typedef __attribute__((ext_vector_type(8))) short bf16x8;
typedef unsigned short u16;
typedef unsigned int u32;

#define QSCALE 0.18033688011112042f  // (1/sqrt(64)) * log2(e), folded into Q proj
#define MASKVAL (-60.0f)             // finite mask: exp2(-60)=8.7e-19, negligible

__device__ __forceinline__ u16 f2bf(float f) {
  union { float f; u32 u; } v; v.f = f;
  u32 r = v.u + 0x7fffu + ((v.u >> 16) & 1u);
  return (u16)(r >> 16);
}

__device__ __forceinline__ u32 cvtpk(float a, float b) {
  u32 r;
  asm("v_cvt_pk_bf16_f32 %0, %1, %2" : "=v"(r) : "v"(a), "v"(b));
  return r;
}

// compiler-visible pack: v_exp_f32 (TRANS) feeding inline-asm gets no
// compiler wait-states (r17-r19); keep all exp consumers intrinsic-visible.
__device__ __forceinline__ u32 cvtpk_safe(float a, float b) {
  __hip_bfloat162 h = __float22bfloat162_rn(float2{a, b});
  union { __hip_bfloat162 h; u32 u; } v; v.h = h;
  return v.u;
}

// native 2^x: single v_exp_f32
__device__ __forceinline__ float nexp2(float x) {
  return __builtin_amdgcn_exp2f(x);
}

// async global->LDS, 16B per lane; LDS dest = base + lane*16 (wave-uniform base)
__device__ __forceinline__ void gl_lds16(const u16* g, u16* l) {
  __builtin_amdgcn_global_load_lds((const __attribute__((address_space(1))) u32*)g,
                                   (__attribute__((address_space(3))) u32*)l, 16, 0, 0);
}

// ---------------- fp32 -> bf16 bulk convert (q,k,v,Wq,Wk,Wv,Wf) ----------------
__global__ __launch_bounds__(256) void conv_kernel(
    const float* __restrict__ q, const float* __restrict__ k, const float* __restrict__ v,
    const float* __restrict__ wq, const float* __restrict__ wk, const float* __restrict__ wv,
    const float* __restrict__ wf, u16* __restrict__ dst)
{
  size_t i = ((size_t)blockIdx.x * 256 + threadIdx.x) * 8;  // 16M elems total
  const float* src; size_t off;
  if (i < ((size_t)3 << 22)) {
    int a = (int)(i >> 22);
    src = (a == 0) ? q : ((a == 1) ? k : v);
    off = i & ((1u << 22) - 1);
  } else {
    size_t j = i - ((size_t)3 << 22);
    int a = (int)(j >> 20);
    src = (a == 0) ? wq : ((a == 1) ? wk : ((a == 2) ? wv : wf));
    off = j & ((1u << 20) - 1);
  }
  float4 x0 = *reinterpret_cast<const float4*>(src + off);
  float4 x1 = *reinterpret_cast<const float4*>(src + off + 4);
  u32 o[4] = {cvtpk(x0.x, x0.y), cvtpk(x0.z, x0.w), cvtpk(x1.x, x1.y), cvtpk(x1.z, x1.w)};
  *reinterpret_cast<uint4*>(dst + i) = *reinterpret_cast<const uint4*>(o);
}

// ---------------- bf16 GEMM: C[M,N]=X[M,K]@W[N,K]^T+b ; BK=64, swizzled LDS ----
struct GArg {
  const u16* X; const u16* W; const float* bias; void* out; int mode; float scale;
};

template<int BM>
__global__ __launch_bounds__(256) void gemm_bf(GArg a0, GArg a1, GArg a2) {
  constexpr int K = 1024, N = 1024;
  constexpr int WNw = (BM == 128) ? 2 : 4;
  constexpr int NI  = (128 / WNw) / 16;
  constexpr int CA  = BM / 32;
  __shared__ __align__(16) u16 lA[BM * 64];
  __shared__ __align__(16) u16 lB[128 * 64];
  GArg a = (blockIdx.z == 0) ? a0 : ((blockIdx.z == 1) ? a1 : a2);
  const int m0 = blockIdx.x * BM, n0 = blockIdx.y * 128;
  const int tid = threadIdx.x, w = tid >> 6, lane = tid & 63;
  const int lr = lane & 15, lg = lane >> 4;
  const int wm = (w / WNw) * 64, wn = (w % WNw) * (128 / WNw);
  const int lrow8 = lane >> 3, lc = lane & 7;
  const int schunk = (lc ^ lrow8) * 8;

  f32x4 acc[4][NI] = {};

  for (int kt = 0; kt < K; kt += 64) {
    #pragma unroll
    for (int c = 0; c < CA; ++c) {
      int row = w * (BM / 4) + c * 8 + lrow8;
      gl_lds16(a.X + (size_t)(m0 + row) * K + kt + schunk, &lA[(w * (BM / 4) + c * 8) * 64]);
    }
    #pragma unroll
    for (int c = 0; c < 4; ++c) {
      int row = w * 32 + c * 8 + lrow8;
      gl_lds16(a.W + (size_t)(n0 + row) * K + kt + schunk, &lB[(w * 32 + c * 8) * 64]);
    }
    __syncthreads();
    #pragma unroll
    for (int h = 0; h < 2; ++h) {
      bf16x8 af[4], bfv[NI];
      #pragma unroll
      for (int i = 0; i < 4; ++i) {
        int r = wm + i * 16 + lr;
        af[i] = *reinterpret_cast<const bf16x8*>(&lA[r * 64 + (((h * 4 + lg) ^ (r & 7)) * 8)]);
      }
      #pragma unroll
      for (int i = 0; i < NI; ++i) {
        int r = wn + i * 16 + lr;
        bfv[i] = *reinterpret_cast<const bf16x8*>(&lB[r * 64 + (((h * 4 + lg) ^ (r & 7)) * 8)]);
      }
      __builtin_amdgcn_s_setprio(1);
      #pragma unroll
      for (int mi = 0; mi < 4; ++mi)
        #pragma unroll
        for (int ni = 0; ni < NI; ++ni)
          acc[mi][ni] = __builtin_amdgcn_mfma_f32_16x16x32_bf16(af[mi], bfv[ni], acc[mi][ni], 0, 0, 0);
      __builtin_amdgcn_s_setprio(0);
    }
    __syncthreads();
  }

  #pragma unroll
  for (int mi = 0; mi < 4; ++mi) {
    #pragma unroll
    for (int ni = 0; ni < NI; ++ni) {
      int col = n0 + wn + ni * 16 + lr;
      float bv = a.bias[col];
      #pragma unroll
      for (int r = 0; r < 4; ++r) {
        int row = m0 + wm + mi * 16 + lg * 4 + r;
        float val = (acc[mi][ni][r] + bv) * a.scale;
        if (a.mode == 2) {
          ((float*)a.out)[(size_t)row * N + col] = val;
        } else {
          int b = row >> 11, s = row & 2047, hh = col >> 6, hd = col & 63;
          u16* O = (u16*)a.out;
          if (a.mode == 0) O[((size_t)(b * 16 + hh) * 2048 + s) * 64 + hd] = f2bf(val);
          else             O[((size_t)(b * 16 + hh) * 64 + hd) * 2048 + s] = f2bf(val);
        }
      }
    }
  }
}

// ---------------- legacy fp32-staging GEMM (ws fallback) -----------------------
template<int IN_BF16, int OUT_MODE>
__global__ __launch_bounds__(256) void gemm_legacy(
    const void* __restrict__ Xv, const float* __restrict__ W,
    const float* __restrict__ bias, void* __restrict__ Outv, float scale)
{
  constexpr int N = 1024, K = 1024;
  __shared__ __align__(16) u16 lA[128 * 32];
  __shared__ __align__(16) u16 lB[128 * 32];
  const int n0 = blockIdx.x * 128, m0 = blockIdx.y * 128;
  const int tid = threadIdx.x;
  const int w = tid >> 6, lane = tid & 63, lr = lane & 15, lg = lane >> 4;
  const int wm = (w >> 1) * 64, wn = (w & 1) * 64;
  f32x4 acc[4][4] = {};
  for (int kt = 0; kt < K; kt += 32) {
    #pragma unroll
    for (int it = 0; it < 4; ++it) {
      int idx = it * 256 + tid, row = idx >> 3, c4 = idx & 7;
      float4 xv = *reinterpret_cast<const float4*>(&W[(size_t)(n0 + row) * K + kt + c4 * 4]);
      u16* dst = &lB[row * 32 + c4 * 4];
      dst[0] = f2bf(xv.x); dst[1] = f2bf(xv.y); dst[2] = f2bf(xv.z); dst[3] = f2bf(xv.w);
    }
    if (IN_BF16 == 0) {
      const float* X = (const float*)Xv;
      #pragma unroll
      for (int it = 0; it < 4; ++it) {
        int idx = it * 256 + tid, row = idx >> 3, c4 = idx & 7;
        float4 xv = *reinterpret_cast<const float4*>(&X[(size_t)(m0 + row) * K + kt + c4 * 4]);
        u16* dst = &lA[row * 32 + c4 * 4];
        dst[0] = f2bf(xv.x); dst[1] = f2bf(xv.y); dst[2] = f2bf(xv.z); dst[3] = f2bf(xv.w);
      }
    } else {
      const u16* X = (const u16*)Xv;
      #pragma unroll
      for (int it = 0; it < 2; ++it) {
        int idx = it * 256 + tid, row = idx >> 2, c = idx & 3;
        *reinterpret_cast<uint4*>(&lA[row * 32 + c * 8]) =
            *reinterpret_cast<const uint4*>(&X[(size_t)(m0 + row) * K + kt + c * 8]);
      }
    }
    __syncthreads();
    bf16x8 af[4], bfr[4];
    #pragma unroll
    for (int i = 0; i < 4; ++i) {
      af[i]  = *reinterpret_cast<const bf16x8*>(&lA[(wm + i * 16 + lr) * 32 + lg * 8]);
      bfr[i] = *reinterpret_cast<const bf16x8*>(&lB[(wn + i * 16 + lr) * 32 + lg * 8]);
    }
    #pragma unroll
    for (int mi = 0; mi < 4; ++mi)
      #pragma unroll
      for (int ni = 0; ni < 4; ++ni)
        acc[mi][ni] = __builtin_amdgcn_mfma_f32_16x16x32_bf16(af[mi], bfr[ni], acc[mi][ni], 0, 0, 0);
    __syncthreads();
  }
  #pragma unroll
  for (int mi = 0; mi < 4; ++mi)
    #pragma unroll
    for (int ni = 0; ni < 4; ++ni) {
      int col = n0 + wn + ni * 16 + lr;
      float bv = bias[col];
      #pragma unroll
      for (int r = 0; r < 4; ++r) {
        int row = m0 + wm + mi * 16 + lg * 4 + r;
        float val = (acc[mi][ni][r] + bv) * scale;
        if (OUT_MODE == 2) {
          ((float*)Outv)[(size_t)row * N + col] = val;
        } else {
          int b = row >> 11, s = row & 2047, h = col >> 6, hd = col & 63;
          u16* O = (u16*)Outv;
          if (OUT_MODE == 0) O[((size_t)(b * 16 + h) * 2048 + s) * 64 + hd] = f2bf(val);
          else               O[((size_t)(b * 16 + h) * 64 + hd) * 2048 + s] = f2bf(val);
        }
      }
    }
}

// ---------------- causal flash attention v8c: balanced co-residency ------------
// Best-known configuration (round 23, 107.45 us total): no-softmax linear
// combine (P = exp2(s) via native v_exp), cvtpk_safe packing (TRANS hazard),
// finite mask, V-read hoist, per-wave swizzled P scratch, double-buffered
// gl_lds staging, bh-fast grid (K/V L2-pinned per XCD), and a t-permutation
// giving the 4 co-scheduled blocks per CU constant total work:
//   y in [0,8): t=31-y ; [8,16): t=y-8 ; [16,24): t=39-y ; [24,32): t=y-16
// (sum over {y, y+8, y+16, y+24} = 62 for every y).

__device__ __forceinline__ void seg_step4(
    const bf16x8* aq, f32x4* oacc, float& ls,
    const u16* lK, const u16* lV, char* pwb,
    bool diag, int col0, int qv, int lr, int lg, bf16x8 ones)
{
  const int cs = lr & 7;
  f32x4 sc[4];
  #pragma unroll
  for (int nf = 0; nf < 4; ++nf) {
    const u16* kr = &lK[(nf * 16 + lr) * 64];
    bf16x8 k0 = *reinterpret_cast<const bf16x8*>(&kr[(lg ^ cs) * 8]);
    bf16x8 k1 = *reinterpret_cast<const bf16x8*>(&kr[((4 + lg) ^ cs) * 8]);
    f32x4 z = {};
    __builtin_amdgcn_s_setprio(1);
    z = __builtin_amdgcn_mfma_f32_16x16x32_bf16(k0, aq[0], z, 0, 0, 0);
    z = __builtin_amdgcn_mfma_f32_16x16x32_bf16(k1, aq[1], z, 0, 0, 0);
    __builtin_amdgcn_s_setprio(0);
    sc[nf] = z;
  }
  // hoisted V fragments: overlap their LDS latency with the exp/pack chain
  bf16x8 vv0[4], vv1[4];
  #pragma unroll
  for (int df = 0; df < 4; ++df) {
    const u16* vr = &lV[(df * 16 + lr) * 64];
    vv0[df] = *reinterpret_cast<const bf16x8*>(&vr[(lg ^ cs) * 8]);
    vv1[df] = *reinterpret_cast<const bf16x8*>(&vr[((4 + lg) ^ cs) * 8]);
  }
  if (diag) {
    #pragma unroll
    for (int nf = 0; nf < 4; ++nf)
      #pragma unroll
      for (int r = 0; r < 4; ++r)
        if ((col0 + nf * 16 + lg * 4 + r) > qv) sc[nf][r] = MASKVAL;
  }
  #pragma unroll
  for (int nf = 0; nf < 4; ++nf) {
    float p0 = nexp2(sc[nf][0]), p1 = nexp2(sc[nf][1]);
    float p2 = nexp2(sc[nf][2]), p3 = nexp2(sc[nf][3]);
    uint2 pr;
    pr.x = cvtpk_safe(p0, p1);
    pr.y = cvtpk_safe(p2, p3);
    *reinterpret_cast<uint2*>(pwb + lr * 128 + ((32 * nf + 8 * lg) ^ (cs << 4))) = pr;
  }
  bf16x8 pb0 = *reinterpret_cast<const bf16x8*>(pwb + lr * 128 + 16 * (lg ^ cs));
  bf16x8 pb1 = *reinterpret_cast<const bf16x8*>(pwb + lr * 128 + 16 * ((4 + lg) ^ cs));
  f32x4 rs = {};
  rs = __builtin_amdgcn_mfma_f32_16x16x32_bf16(ones, pb0, rs, 0, 0, 0);
  rs = __builtin_amdgcn_mfma_f32_16x16x32_bf16(ones, pb1, rs, 0, 0, 0);
  ls += rs[0];
  #pragma unroll
  for (int df = 0; df < 4; ++df) {
    __builtin_amdgcn_s_setprio(1);
    oacc[df] = __builtin_amdgcn_mfma_f32_16x16x32_bf16(vv0[df], pb0, oacc[df], 0, 0, 0);
    oacc[df] = __builtin_amdgcn_mfma_f32_16x16x32_bf16(vv1[df], pb1, oacc[df], 0, 0, 0);
    __builtin_amdgcn_s_setprio(0);
  }
}

__global__ __launch_bounds__(256) void attn_kernel8(
    const u16* __restrict__ Qh, const u16* __restrict__ Kh,
    const u16* __restrict__ Vt, u16* __restrict__ Oa)
{
  __shared__ __align__(16) u16 lK[2][64 * 64];
  __shared__ __align__(16) u16 lV[2][64 * 64];
  __shared__ __align__(16) u16 lP[4][16 * 64];
  const int bh = blockIdx.x;            // bh-fast: head -> fixed XCD
  const int y = blockIdx.y;             // balanced-residency t-permutation
  const int t = (y < 8) ? (31 - y) : ((y < 16) ? (y - 8) : ((y < 24) ? (39 - y) : (y - 16)));
  const int b = bh >> 4, h = bh & 15;
  const u16* Qb = Qh + (size_t)bh * 2048 * 64;
  const u16* Kb = Kh + (size_t)bh * 2048 * 64;
  const u16* Vb = Vt + (size_t)bh * 64 * 2048;
  const int tid = threadIdx.x, w = tid >> 6, lane = tid & 63;
  const int lr = lane & 15, lg = lane >> 4;
  const int lrow8 = lane >> 3, lc = lane & 7;
  const int schunk = (lc ^ lrow8) * 8;
  char* pwb = (char*)lP[w];

  bf16x8 ones;
  #pragma unroll
  for (int j = 0; j < 8; ++j) ones[j] = (short)0x3F80;

  bf16x8 aq[2];
  {
    int qrow = t * 64 + w * 16 + lr;
    aq[0] = *reinterpret_cast<const bf16x8*>(&Qb[(size_t)qrow * 64 + lg * 8]);
    aq[1] = *reinterpret_cast<const bf16x8*>(&Qb[(size_t)qrow * 64 + 32 + lg * 8]);
  }
  f32x4 oacc[4] = {};
  float ls = 0.f;
  const int qv = t * 64 + w * 16 + lr;

  const int nkt = t + 1;
  int cur = 0;

  #pragma unroll
  for (int c = 0; c < 2; ++c) {
    int row = w * 16 + c * 8 + lrow8;
    gl_lds16(Kb + (size_t)row * 64 + schunk, &lK[0][(w * 16 + c * 8) * 64]);
    gl_lds16(Vb + (size_t)row * 2048 + schunk, &lV[0][(w * 16 + c * 8) * 64]);
  }
  __syncthreads();

  for (int kt = 0; kt < nkt; ++kt) {
    if (kt + 1 < nkt) {
      #pragma unroll
      for (int c = 0; c < 2; ++c) {
        int row = w * 16 + c * 8 + lrow8;
        gl_lds16(Kb + (size_t)((kt + 1) * 64 + row) * 64 + schunk, &lK[cur ^ 1][(w * 16 + c * 8) * 64]);
        gl_lds16(Vb + (size_t)row * 2048 + (kt + 1) * 64 + schunk, &lV[cur ^ 1][(w * 16 + c * 8) * 64]);
      }
    }
    seg_step4(aq, oacc, ls, lK[cur], lV[cur], pwb, kt == t, kt * 64, qv, lr, lg, ones);
    if (kt + 1 < nkt) __syncthreads();
    cur ^= 1;
  }

  float inv = 1.0f / ls;
  #pragma unroll
  for (int df = 0; df < 4; ++df) {
    uint2 pa;
    pa.x = cvtpk(oacc[df][0] * inv, oacc[df][1] * inv);
    pa.y = cvtpk(oacc[df][2] * inv, oacc[df][3] * inv);
    *reinterpret_cast<uint2*>(&Oa[(size_t)(b * 2048 + qv) * 1024 + h * 64 + df * 16 + lg * 4]) = pa;
  }
}

extern "C" void kernel_launch(void* const* d_in, const int* in_sizes, int n_in,
                              void* d_out, int out_size, void* d_ws, size_t ws_size,
                              hipStream_t stream) {
  const float* q  = (const float*)d_in[0];
  const float* k  = (const float*)d_in[1];
  const float* v  = (const float*)d_in[2];
  const float* Wq = (const float*)d_in[4];
  const float* bq = (const float*)d_in[5];
  const float* Wk = (const float*)d_in[6];
  const float* bk = (const float*)d_in[7];
  const float* Wv = (const float*)d_in[8];
  const float* bv = (const float*)d_in[9];
  const float* Wf = (const float*)d_in[10];
  const float* bf = (const float*)d_in[11];

  if (ws_size >= ((size_t)64 << 20)) {
    u16* wsb = (u16*)d_ws;
    u16* qb  = wsb;
    u16* kb  = wsb + (1u << 22);
    u16* vb  = wsb + ((size_t)2 << 22);
    u16* wqb = wsb + ((size_t)3 << 22);
    u16* wkb = wqb + (1u << 20);
    u16* wvb = wkb + (1u << 20);
    u16* wfb = wvb + (1u << 20);
    u16* Qh  = wsb + ((size_t)1 << 24);
    u16* Kh  = Qh + (1u << 22);
    u16* Vt  = Kh + (1u << 22);
    u16* Oa  = Vt + (1u << 22);

    conv_kernel<<<8192, 256, 0, stream>>>(q, k, v, Wq, Wk, Wv, Wf, wsb);

    GArg gq{qb, wqb, bq, Qh, 0, QSCALE};
    GArg gk{kb, wkb, bk, Kh, 0, 1.0f};
    GArg gv{vb, wvb, bv, Vt, 1, 1.0f};
    gemm_bf<128><<<dim3(32, 8, 3), 256, 0, stream>>>(gq, gk, gv);

    attn_kernel8<<<dim3(32, 32), 256, 0, stream>>>(Qh, Kh, Vt, Oa);

    GArg gf{Oa, wfb, bf, d_out, 2, 1.0f};
    gemm_bf<64><<<dim3(64, 8, 1), 256, 0, stream>>>(gf, gf, gf);
  } else {
    // fallback: fp32-staging GEMMs (32 MB ws)
    u16* Qh = (u16*)d_ws;
    u16* Kh = Qh + (size_t)4096 * 1024;
    u16* Vt = Kh + (size_t)4096 * 1024;
    u16* Oa = Vt + (size_t)4096 * 1024;
    dim3 gg(8, 32), gb(256);
    gemm_legacy<0, 0><<<gg, gb, 0, stream>>>(q, Wq, bq, Qh, QSCALE);
    gemm_legacy<0, 0><<<gg, gb, 0, stream>>>(k, Wk, bk, Kh, 1.0f);
    gemm_legacy<0, 1><<<gg, gb, 0, stream>>>(v, Wv, bv, Vt, 1.0f);
    attn_kernel8<<<dim3(32, 32), gb, 0, stream>>>(Qh, Kh, Vt, Oa);
    gemm_legacy<1, 2><<<gg, gb, 0, stream>>>(Oa, Wf, bf, (float*)d_out, 1.0f);
  }
}